// Round 1
// baseline (712.222 us; speedup 1.0000x reference)
//
#include <hip/hip_runtime.h>
#include <math.h>

#define N_PATHS 23
#define HIDDEN  32
#define N_NODES 4096
#define N_EDGES 8192
#define FEAT    512
#define C_TOTAL 1875
#define Z_TOTAL 439
#define T_TOTAL 3168

// ---- path metadata (PATHS enumeration order: l1 outer, l2, l3) ----
__device__ const int P_L1[N_PATHS] = {0,0,0,0, 1,1,1,1,1,1, 2,2,2,2,2,2,2, 3,3,3,3,3,3};
__device__ const int P_L2[N_PATHS] = {0,1,2,3, 0,1,1,2,2,3, 0,1,1,2,2,3,3, 0,1,2,2,3,3};
__device__ const int P_L3[N_PATHS] = {0,1,2,3, 1,0,2,1,3,2, 2,1,3,0,2,1,3, 3,2,1,3,0,2};
__device__ const int C_OFF[N_PATHS] = {0,1,10,35,84,93,102,147,192,297,402,427,472,577,602,727,832,1077,1126,1231,1336,1581,1630};
__device__ const int Z_OFF[N_PATHS] = {0,1,4,9,16,25,28,43,52,73,88,113,128,163,168,193,208,243,292,327,348,397,404};
__device__ const int T_OFF[N_PATHS] = {0,32,128,288,512,608,640,800,896,1120,1280,1440,1536,1760,1792,1952,2048,2272,2496,2656,2752,2976,3008};
// paths grouped by l3
__device__ const int L3PATHS[N_PATHS] = {0,5,13,21, 1,4,7,11,15,19, 2,6,9,10,14,18,22, 3,8,12,16,17,20};
__device__ const int L3START[5] = {0,4,10,17,23};
__device__ const int CNT_L3[4] = {4,6,7,6};

// ---- 16-point Gauss-Legendre nodes/weights (order irrelevant for the sum) ----
__device__ const double GLX[16] = {
    -0.98940093499164993, -0.94457502307323258, -0.86563120238783174, -0.75540440835500303,
    -0.61787624440264375, -0.45801677765722739, -0.28160355077925891, -0.09501250983763744,
     0.09501250983763744,  0.28160355077925891,  0.45801677765722739,  0.61787624440264375,
     0.75540440835500303,  0.86563120238783174,  0.94457502307323258,  0.98940093499164993};
__device__ const double GLW[16] = {
     0.02715245941175409,  0.06225352393864789,  0.09515851168249278,  0.12462897125553387,
     0.14959598881657673,  0.16915651939500254,  0.18260341504492359,  0.18945061045506850,
     0.18945061045506850,  0.18260341504492359,  0.16915651939500254,  0.14959598881657673,
     0.12462897125553387,  0.09515851168249278,  0.06225352393864789,  0.02715245941175409};

__device__ inline void sh_f64(double x, double y, double z, double* Y) {
    const double s3 = sqrt(3.0), s5 = sqrt(5.0), s7 = sqrt(7.0), s15 = sqrt(15.0);
    const double c58 = sqrt(5.0/8.0), c38 = sqrt(3.0/8.0);
    Y[0] = 1.0;
    Y[1] = s3*x;  Y[2] = s3*y;  Y[3] = s3*z;
    Y[4] = s5*s3*x*z;
    Y[5] = s5*s3*x*y;
    Y[6] = s5*(y*y - 0.5*(x*x + z*z));
    Y[7] = s5*s3*y*z;
    Y[8] = s5*(s3/2.0)*(z*z - x*x);
    Y[9] = s7*c58*x*(3.0*z*z - x*x);
    Y[10]= s7*s15*x*y*z;
    Y[11]= s7*c38*x*(5.0*y*y - 1.0);
    Y[12]= s7*0.5*y*(5.0*y*y - 3.0);
    Y[13]= s7*c38*z*(5.0*y*y - 1.0);
    Y[14]= s7*(s15/2.0)*y*(z*z - x*x);
    Y[15]= s7*c58*z*(z*z - 3.0*x*x);
}

__device__ inline void sh_f32(float x, float y, float z, float* Y) {
    const float s3 = 1.73205080757f, s5 = 2.23606797750f, s7 = 2.64575131106f, s15 = 3.87298334621f;
    const float c58 = 0.79056941504f, c38 = 0.61237243570f;
    Y[0] = 1.0f;
    Y[1] = s3*x;  Y[2] = s3*y;  Y[3] = s3*z;
    Y[4] = s15*x*z;
    Y[5] = s15*x*y;
    Y[6] = s5*(y*y - 0.5f*(x*x + z*z));
    Y[7] = s15*y*z;
    Y[8] = s5*(s3*0.5f)*(z*z - x*x);
    Y[9] = s7*c58*x*(3.0f*z*z - x*x);
    Y[10]= s7*s15*x*y*z;
    Y[11]= s7*c38*x*(5.0f*y*y - 1.0f);
    Y[12]= s7*0.5f*y*(5.0f*y*y - 3.0f);
    Y[13]= s7*c38*z*(5.0f*y*y - 1.0f);
    Y[14]= s7*(s15*0.5f)*y*(z*z - x*x);
    Y[15]= s7*c58*z*(z*z - 3.0f*x*x);
}

__device__ inline int find_path(const int* off, int idx) {
    int p = 0;
#pragma unroll
    for (int q = 1; q < N_PATHS; ++q) p += (off[q] <= idx) ? 1 : 0;
    return p;
}

// ---- setup: build (PATH_W * W3J / ||W3J||) tables in fp64, store fp32 into d_ws ----
__global__ __launch_bounds__(256) void w3j_setup_kernel(float* __restrict__ g_w3j) {
    const int p = blockIdx.x;
    const int t = threadIdx.x;
    const int l1 = P_L1[p], l2 = P_L2[p], l3 = P_L3[p];
    const int d1 = 2*l1+1, d2 = 2*l2+1, d3 = 2*l3+1;
    const int csize = d1*d2*d3;

    const int idx0 = t, idx1 = t + 256;
    const bool v0 = idx0 < csize, v1 = idx1 < csize;
    int i0=0,j0=0,k0=0, i1=0,j1=0,k1=0;
    if (v0) { i0 = idx0/(d2*d3); int r = idx0 - i0*(d2*d3); j0 = r/d3; k0 = r - j0*d3; }
    if (v1) { i1 = idx1/(d2*d3); int r = idx1 - i1*(d2*d3); j1 = r/d3; k1 = r - j1*d3; }

    const double PI = 3.141592653589793;
    const double step = 2.0*PI/32.0;
    double a0 = 0.0, a1 = 0.0;
    for (int q = 0; q < 512; ++q) {
        const int iu = q >> 5, ip = q & 31;
        const double u  = GLX[iu];
        const double wq = GLW[iu] * step;
        const double phi = (double)ip * step;
        const double st = sqrt(fmax(1.0 - u*u, 0.0));
        const double x = st*cos(phi), y = st*sin(phi), z = u;
        double Y[16];
        sh_f64(x, y, z, Y);
        if (v0) a0 += wq * Y[l1*l1+i0] * Y[l2*l2+j0] * Y[l3*l3+k0];
        if (v1) a1 += wq * Y[l1*l1+i1] * Y[l2*l2+j1] * Y[l3*l3+k1];
    }

    __shared__ double red[256];
    __shared__ double s_scale;
    red[t] = a0*a0 + a1*a1;
    __syncthreads();
    for (int s = 128; s > 0; s >>= 1) {
        if (t < s) red[t] += red[t+s];
        __syncthreads();
    }
    if (t == 0) {
        const double nrm = sqrt(red[0]);
        const double pw  = sqrt((double)(2*l3+1) / ((double)CNT_L3[l3] * (double)HIDDEN));
        s_scale = pw / nrm;
    }
    __syncthreads();
    if (v0) g_w3j[C_OFF[p] + idx0] = (float)(a0 * s_scale);
    if (v1) g_w3j[C_OFF[p] + idx1] = (float)(a1 * s_scale);
}

// ---- main: one block per edge ----
__global__ __launch_bounds__(256) void edge_kernel(
    const float* __restrict__ nf,   // (N_NODES, FEAT)
    const int*   __restrict__ eidx, // (2, N_EDGES)
    const float* __restrict__ ev,   // (N_EDGES, 3)
    const float* __restrict__ ww,   // (23552,)
    const float* __restrict__ wb,   // (23552,)
    const float* __restrict__ w3j,  // (1875,)
    float*       __restrict__ out)  // (N_NODES, FEAT) pre-zeroed
{
    __shared__ float s_x[FEAT];
    __shared__ float s_Y[16];
    __shared__ float s_len;
    __shared__ float s_C[C_TOTAL];
    __shared__ float s_z[Z_TOTAL];
    __shared__ float s_tmp[T_TOTAL];

    const int e = blockIdx.x;
    const int t = threadIdx.x;
    const int src = eidx[e];
    const int dst = eidx[N_EDGES + e];

    // stage gathered node features + W3J table
    s_x[t]       = nf[src*FEAT + t];
    s_x[t + 256] = nf[src*FEAT + t + 256];
    for (int i = t; i < C_TOTAL; i += 256) s_C[i] = w3j[i];
    if (t == 0) {
        const float x = ev[e*3+0], y = ev[e*3+1], z = ev[e*3+2];
        const float len = sqrtf(x*x + y*y + z*z);
        const float lc = fmaxf(len, 1e-8f);
        s_len = lc;
        float Yl[16];
        sh_f32(x/lc, y/lc, z/lc, Yl);
#pragma unroll
        for (int i = 0; i < 16; ++i) s_Y[i] = Yl[i];
    }
    __syncthreads();

    // z[p][i][k] = sum_j Y[l2^2+j] * C[p][i][j][k]
    for (int idx = t; idx < Z_TOTAL; idx += 256) {
        const int p = find_path(Z_OFF, idx);
        const int l2 = P_L2[p], l3 = P_L3[p];
        const int d2 = 2*l2+1, d3 = 2*l3+1;
        const int loc = idx - Z_OFF[p];
        const int i = loc / d3, k = loc - (loc/d3)*d3;
        const float* Cp = &s_C[C_OFF[p] + i*d2*d3 + k];
        const float* Yp = &s_Y[l2*l2];
        float acc = 0.0f;
        for (int j = 0; j < d2; ++j) acc += Yp[j] * Cp[j*d3];
        s_z[idx] = acc;
    }
    __syncthreads();

    // tmp[p][u][k] = sum_i x1[u][i] * z[p][i][k]
    for (int idx = t; idx < T_TOTAL; idx += 256) {
        const int p = find_path(T_OFF, idx);
        const int l1 = P_L1[p], l3 = P_L3[p];
        const int d1 = 2*l1+1, d3 = 2*l3+1;
        const int loc = idx - T_OFF[p];
        const int u = loc / d3, k = loc - (loc/d3)*d3;
        const float* xr = &s_x[HIDDEN*l1*l1 + u*d1];
        const float* zr = &s_z[Z_OFF[p] + k];
        float acc = 0.0f;
        for (int i = 0; i < d1; ++i) acc += xr[i] * zr[i*d3];
        s_tmp[idx] = acc;
    }
    __syncthreads();

    // out[w][k] over all l3: len * (tmp . ww) + (tmp . wb), atomic scatter to dst
    const float len = s_len;
    for (int m = t; m < FEAT; m += 256) {
        int l3, w, k;
        if (m < 32)       { l3 = 0; w = m;          k = 0; }
        else if (m < 128) { l3 = 1; int r = m-32;  w = r/3; k = r-3*(r/3); }
        else if (m < 288) { l3 = 2; int r = m-128; w = r/5; k = r-5*(r/5); }
        else              { l3 = 3; int r = m-288; w = r/7; k = r-7*(r/7); }
        const int d3 = 2*l3+1;
        float acc_w = 0.0f, acc_b = 0.0f;
        for (int pi = L3START[l3]; pi < L3START[l3+1]; ++pi) {
            const int p = L3PATHS[pi];
            const float* tp  = &s_tmp[T_OFF[p] + k];
            const float* wwp = &ww[p*HIDDEN*HIDDEN + w];
            const float* wbp = &wb[p*HIDDEN*HIDDEN + w];
#pragma unroll
            for (int u = 0; u < HIDDEN; ++u) {
                const float tv = tp[u*d3];
                acc_w += tv * wwp[u*HIDDEN];
                acc_b += tv * wbp[u*HIDDEN];
            }
        }
        atomicAdd(&out[dst*FEAT + m], len*acc_w + acc_b);
    }
}

extern "C" void kernel_launch(void* const* d_in, const int* in_sizes, int n_in,
                              void* d_out, int out_size, void* d_ws, size_t ws_size,
                              hipStream_t stream) {
    const float* nf   = (const float*)d_in[0];
    const int*   eidx = (const int*)  d_in[1];
    const float* ev   = (const float*)d_in[2];
    const float* ww   = (const float*)d_in[3];
    const float* wb   = (const float*)d_in[4];
    float* out  = (float*)d_out;
    float* w3j  = (float*)d_ws;

    hipMemsetAsync(d_out, 0, (size_t)out_size * sizeof(float), stream);
    w3j_setup_kernel<<<N_PATHS, 256, 0, stream>>>(w3j);
    edge_kernel<<<N_EDGES, 256, 0, stream>>>(nf, eidx, ev, ww, wb, w3j, out);
}

// Round 2
// 469.681 us; speedup vs baseline: 1.5164x; 1.5164x over previous
//
#include <hip/hip_runtime.h>
#include <math.h>

#define N_PATHS 23
#define HIDDEN  32
#define N_NODES 4096
#define N_EDGES 8192
#define FEAT    512
#define C_TOTAL 1875
#define Z_TOTAL 439
#define T_TOTAL 3168

// ---- path metadata (PATHS enumeration order: l1 outer, l2, l3) ----
__device__ const int P_L1[N_PATHS] = {0,0,0,0, 1,1,1,1,1,1, 2,2,2,2,2,2,2, 3,3,3,3,3,3};
__device__ const int P_L2[N_PATHS] = {0,1,2,3, 0,1,1,2,2,3, 0,1,1,2,2,3,3, 0,1,2,2,3,3};
__device__ const int P_L3[N_PATHS] = {0,1,2,3, 1,0,2,1,3,2, 2,1,3,0,2,1,3, 3,2,1,3,0,2};
__device__ const int C_OFF[N_PATHS] = {0,1,10,35,84,93,102,147,192,297,402,427,472,577,602,727,832,1077,1126,1231,1336,1581,1630};
__device__ const int Z_OFF[N_PATHS] = {0,1,4,9,16,25,28,43,52,73,88,113,128,163,168,193,208,243,292,327,348,397,404};
__device__ const int T_OFF[N_PATHS] = {0,32,128,288,512,608,640,800,896,1120,1280,1440,1536,1760,1792,1952,2048,2272,2496,2656,2752,2976,3008};
// paths grouped by l3 (so consecutive (p,w) pairs share d3 within a wave)
__device__ const int L3PATHS[N_PATHS] = {0,5,13,21, 1,4,7,11,15,19, 2,6,9,10,14,18,22, 3,8,12,16,17,20};
__device__ const int L3START[5] = {0,4,10,17,23};
__device__ const int CNT_L3[4] = {4,6,7,6};
__device__ const int OFF3[4] = {0,32,128,288};

// ---- 16-point Gauss-Legendre nodes/weights ----
__device__ const double GLX[16] = {
    -0.98940093499164993, -0.94457502307323258, -0.86563120238783174, -0.75540440835500303,
    -0.61787624440264375, -0.45801677765722739, -0.28160355077925891, -0.09501250983763744,
     0.09501250983763744,  0.28160355077925891,  0.45801677765722739,  0.61787624440264375,
     0.75540440835500303,  0.86563120238783174,  0.94457502307323258,  0.98940093499164993};
__device__ const double GLW[16] = {
     0.02715245941175409,  0.06225352393864789,  0.09515851168249278,  0.12462897125553387,
     0.14959598881657673,  0.16915651939500254,  0.18260341504492359,  0.18945061045506850,
     0.18945061045506850,  0.18260341504492359,  0.16915651939500254,  0.14959598881657673,
     0.12462897125553387,  0.09515851168249278,  0.06225352393864789,  0.02715245941175409};

// cos/sin(k*pi/16), k=0..31 — exact literals, no device transcendentals
__device__ const double COSP[32] = {
  1.0,                    0.980785280403230449,  0.923879532511286756,  0.831469612302545237,
  0.707106781186547524,   0.555570233019602225,  0.382683432365089772,  0.195090322016128268,
  0.0,                   -0.195090322016128268, -0.382683432365089772, -0.555570233019602225,
 -0.707106781186547524,  -0.831469612302545237, -0.923879532511286756, -0.980785280403230449,
 -1.0,                   -0.980785280403230449, -0.923879532511286756, -0.831469612302545237,
 -0.707106781186547524,  -0.555570233019602225, -0.382683432365089772, -0.195090322016128268,
  0.0,                    0.195090322016128268,  0.382683432365089772,  0.555570233019602225,
  0.707106781186547524,   0.831469612302545237,  0.923879532511286756,  0.980785280403230449};
__device__ const double SINP[32] = {
  0.0,                    0.195090322016128268,  0.382683432365089772,  0.555570233019602225,
  0.707106781186547524,   0.831469612302545237,  0.923879532511286756,  0.980785280403230449,
  1.0,                    0.980785280403230449,  0.923879532511286756,  0.831469612302545237,
  0.707106781186547524,   0.555570233019602225,  0.382683432365089772,  0.195090322016128268,
  0.0,                   -0.195090322016128268, -0.382683432365089772, -0.555570233019602225,
 -0.707106781186547524,  -0.831469612302545237, -0.923879532511286756, -0.980785280403230449,
 -1.0,                   -0.980785280403230449, -0.923879532511286756, -0.831469612302545237,
 -0.707106781186547524,  -0.555570233019602225, -0.382683432365089772, -0.195090322016128268};

__device__ inline void sh_f64(double x, double y, double z, double* Y) {
    const double s3 = 1.7320508075688772935, s5 = 2.2360679774997896964,
                 s7 = 2.6457513110645905905, s15 = 3.8729833462074168852;
    const double c58 = 0.79056941504209483300, c38 = 0.61237243569579452455;
    Y[0] = 1.0;
    Y[1] = s3*x;  Y[2] = s3*y;  Y[3] = s3*z;
    Y[4] = s5*s3*x*z;
    Y[5] = s5*s3*x*y;
    Y[6] = s5*(y*y - 0.5*(x*x + z*z));
    Y[7] = s5*s3*y*z;
    Y[8] = s5*(s3/2.0)*(z*z - x*x);
    Y[9] = s7*c58*x*(3.0*z*z - x*x);
    Y[10]= s7*s15*x*y*z;
    Y[11]= s7*c38*x*(5.0*y*y - 1.0);
    Y[12]= s7*0.5*y*(5.0*y*y - 3.0);
    Y[13]= s7*c38*z*(5.0*y*y - 1.0);
    Y[14]= s7*(s15/2.0)*y*(z*z - x*x);
    Y[15]= s7*c58*z*(z*z - 3.0*x*x);
}

__device__ inline void sh_f32(float x, float y, float z, float* Y) {
    const float s3 = 1.73205080757f, s5 = 2.23606797750f, s7 = 2.64575131106f, s15 = 3.87298334621f;
    const float c58 = 0.79056941504f, c38 = 0.61237243570f;
    Y[0] = 1.0f;
    Y[1] = s3*x;  Y[2] = s3*y;  Y[3] = s3*z;
    Y[4] = s15*x*z;
    Y[5] = s15*x*y;
    Y[6] = s5*(y*y - 0.5f*(x*x + z*z));
    Y[7] = s15*y*z;
    Y[8] = s5*(s3*0.5f)*(z*z - x*x);
    Y[9] = s7*c58*x*(3.0f*z*z - x*x);
    Y[10]= s7*s15*x*y*z;
    Y[11]= s7*c38*x*(5.0f*y*y - 1.0f);
    Y[12]= s7*0.5f*y*(5.0f*y*y - 3.0f);
    Y[13]= s7*c38*z*(5.0f*y*y - 1.0f);
    Y[14]= s7*(s15*0.5f)*y*(z*z - x*x);
    Y[15]= s7*c58*z*(z*z - 3.0f*x*x);
}

__device__ inline int find_path(const int* off, int idx) {
    int p = 0;
#pragma unroll
    for (int q = 1; q < N_PATHS; ++q) p += (off[q] <= idx) ? 1 : 0;
    return p;
}

// ---- setup: build (PATH_W * W3J / ||W3J||) tables; quadrature Y staged in LDS ----
__global__ __launch_bounds__(256) void w3j_setup_kernel(float* __restrict__ g_w3j) {
    __shared__ float s_Yq[512][16];
    __shared__ float s_wq[512];
    __shared__ double red[256];
    __shared__ double s_scale;

    const int p = blockIdx.x;
    const int t = threadIdx.x;
    const int l1 = P_L1[p], l2 = P_L2[p], l3 = P_L3[p];
    const int d1 = 2*l1+1, d2 = 2*l2+1, d3 = 2*l3+1;
    const int csize = d1*d2*d3;

    const double step = 2.0*3.14159265358979323846/32.0;

    // phase A: each thread computes 2 quadrature points (fp64, no transcendentals)
#pragma unroll
    for (int r = 0; r < 2; ++r) {
        const int q = t + 256*r;
        const int iu = q >> 5, ip = q & 31;
        const double u = GLX[iu];
        const double st = sqrt(fmax(1.0 - u*u, 0.0));
        double Y[16];
        sh_f64(st*COSP[ip], st*SINP[ip], u, Y);
#pragma unroll
        for (int i = 0; i < 16; ++i) s_Yq[q][i] = (float)Y[i];
        s_wq[q] = (float)(GLW[iu] * step);
    }
    __syncthreads();

    // phase B: each thread accumulates up to 2 C entries (fp32 products, fp64 acc)
    const int idx0 = t, idx1 = t + 256;
    const bool v0 = idx0 < csize, v1 = idx1 < csize;
    int a0i=0,b0i=0,c0i=0, a1i=0,b1i=0,c1i=0;
    if (v0) { int i = idx0/(d2*d3); int r = idx0 - i*(d2*d3); int j = r/d3; int k = r - j*d3;
              a0i = l1*l1+i; b0i = l2*l2+j; c0i = l3*l3+k; }
    if (v1) { int i = idx1/(d2*d3); int r = idx1 - i*(d2*d3); int j = r/d3; int k = r - j*d3;
              a1i = l1*l1+i; b1i = l2*l2+j; c1i = l3*l3+k; }

    double a0 = 0.0, a1 = 0.0;
    for (int q = 0; q < 512; ++q) {
        const float wq = s_wq[q];
        if (v0) a0 += (double)(wq * s_Yq[q][a0i] * s_Yq[q][b0i] * s_Yq[q][c0i]);
        if (v1) a1 += (double)(wq * s_Yq[q][a1i] * s_Yq[q][b1i] * s_Yq[q][c1i]);
    }

    red[t] = a0*a0 + a1*a1;
    __syncthreads();
    for (int s = 128; s > 0; s >>= 1) {
        if (t < s) red[t] += red[t+s];
        __syncthreads();
    }
    if (t == 0) {
        const double nrm = sqrt(red[0]);
        const double pw  = sqrt((double)(2*l3+1) / ((double)CNT_L3[l3] * (double)HIDDEN));
        s_scale = pw / nrm;
    }
    __syncthreads();
    if (v0) g_w3j[C_OFF[p] + idx0] = (float)(a0 * s_scale);
    if (v1) g_w3j[C_OFF[p] + idx1] = (float)(a1 * s_scale);
}

// ---- main: one block per edge ----
__global__ __launch_bounds__(256) void edge_kernel(
    const float* __restrict__ nf,   // (N_NODES, FEAT)
    const int*   __restrict__ eidx, // (2, N_EDGES)
    const float* __restrict__ ev,   // (N_EDGES, 3)
    const float* __restrict__ ww,   // (23552,)
    const float* __restrict__ wb,   // (23552,)
    const float* __restrict__ w3j,  // (1875,)
    float*       __restrict__ out)  // (N_NODES, FEAT) pre-zeroed
{
    __shared__ float s_x[FEAT];
    __shared__ float s_Y[16];
    __shared__ float s_len;
    __shared__ float s_C[C_TOTAL];
    __shared__ float s_z[Z_TOTAL];
    __shared__ float s_tmp[T_TOTAL];
    __shared__ float s_msg[FEAT];

    const int e = blockIdx.x;
    const int t = threadIdx.x;
    const int src = eidx[e];
    const int dst = eidx[N_EDGES + e];

    // stage gathered node features + W3J table; zero message accumulator
    s_x[t]       = nf[src*FEAT + t];
    s_x[t + 256] = nf[src*FEAT + t + 256];
    s_msg[t] = 0.0f; s_msg[t + 256] = 0.0f;
    for (int i = t; i < C_TOTAL; i += 256) s_C[i] = w3j[i];
    if (t == 0) {
        const float x = ev[e*3+0], y = ev[e*3+1], z = ev[e*3+2];
        const float len = sqrtf(x*x + y*y + z*z);
        const float lc = fmaxf(len, 1e-8f);
        s_len = lc;
        float Yl[16];
        sh_f32(x/lc, y/lc, z/lc, Yl);
#pragma unroll
        for (int i = 0; i < 16; ++i) s_Y[i] = Yl[i];
    }
    __syncthreads();

    // z[p][i][k] = sum_j Y[l2^2+j] * C[p][i][j][k]
    for (int idx = t; idx < Z_TOTAL; idx += 256) {
        const int p = find_path(Z_OFF, idx);
        const int l2 = P_L2[p], l3 = P_L3[p];
        const int d2 = 2*l2+1, d3 = 2*l3+1;
        const int loc = idx - Z_OFF[p];
        const int i = loc / d3, k = loc - (loc/d3)*d3;
        const float* Cp = &s_C[C_OFF[p] + i*d2*d3 + k];
        const float* Yp = &s_Y[l2*l2];
        float acc = 0.0f;
        for (int j = 0; j < d2; ++j) acc += Yp[j] * Cp[j*d3];
        s_z[idx] = acc;
    }
    __syncthreads();

    // tmp[p][u][k] = sum_i x1[u][i] * z[p][i][k]
    for (int idx = t; idx < T_TOTAL; idx += 256) {
        const int p = find_path(T_OFF, idx);
        const int l1 = P_L1[p], l3 = P_L3[p];
        const int d1 = 2*l1+1, d3 = 2*l3+1;
        const int loc = idx - T_OFF[p];
        const int u = loc / d3, k = loc - (loc/d3)*d3;
        const float* xr = &s_x[HIDDEN*l1*l1 + u*d1];
        const float* zr = &s_z[Z_OFF[p] + k];
        float acc = 0.0f;
        for (int i = 0; i < d1; ++i) acc += xr[i] * zr[i*d3];
        s_tmp[idx] = acc;
    }
    __syncthreads();

    // epilogue: threads over (path, w) pairs — each weight read exactly once.
    // msg[OFF3[l3] + w*d3 + k] += sum_u tmp_p[u][k] * (len*ww + wb)[u][w]
    const float len = s_len;
    for (int q = t; q < N_PATHS*HIDDEN; q += 256) {
        const int pi = q >> 5;            // path slot (l3-grouped order)
        const int w  = q & 31;
        const int p  = L3PATHS[pi];
        const int l3 = P_L3[p];
        const int d3 = 2*l3+1;
        const float* tp  = &s_tmp[T_OFF[p]];
        const float* wwp = &ww[p*HIDDEN*HIDDEN + w];
        const float* wbp = &wb[p*HIDDEN*HIDDEN + w];
        float accw[7] = {0,0,0,0,0,0,0};
        float accb[7] = {0,0,0,0,0,0,0};
#pragma unroll 4
        for (int u = 0; u < HIDDEN; ++u) {
            const float wwv = wwp[u*HIDDEN];
            const float wbv = wbp[u*HIDDEN];
            const float* tu = &tp[u*d3];
#pragma unroll
            for (int k = 0; k < 7; ++k) {
                if (k < d3) {
                    const float tv = tu[k];
                    accw[k] += tv * wwv;
                    accb[k] += tv * wbv;
                }
            }
        }
        const int base = OFF3[l3] + w*d3;
#pragma unroll
        for (int k = 0; k < 7; ++k) {
            if (k < d3) atomicAdd(&s_msg[base + k], len*accw[k] + accb[k]);
        }
    }
    __syncthreads();

    // one coalesced global atomic per output element
    atomicAdd(&out[dst*FEAT + t],       s_msg[t]);
    atomicAdd(&out[dst*FEAT + t + 256], s_msg[t + 256]);
}

extern "C" void kernel_launch(void* const* d_in, const int* in_sizes, int n_in,
                              void* d_out, int out_size, void* d_ws, size_t ws_size,
                              hipStream_t stream) {
    const float* nf   = (const float*)d_in[0];
    const int*   eidx = (const int*)  d_in[1];
    const float* ev   = (const float*)d_in[2];
    const float* ww   = (const float*)d_in[3];
    const float* wb   = (const float*)d_in[4];
    float* out  = (float*)d_out;
    float* w3j  = (float*)d_ws;

    hipMemsetAsync(d_out, 0, (size_t)out_size * sizeof(float), stream);
    w3j_setup_kernel<<<N_PATHS, 256, 0, stream>>>(w3j);
    edge_kernel<<<N_EDGES, 256, 0, stream>>>(nf, eidx, ev, ww, wb, w3j, out);
}

// Round 3
// 270.951 us; speedup vs baseline: 2.6286x; 1.7335x over previous
//
#include <hip/hip_runtime.h>
#include <math.h>

#define N_PATHS 23
#define HIDDEN  32
#define N_NODES 4096
#define N_EDGES 8192
#define FEAT    512
#define EB      8     // edges per block

// ---- path metadata (PATHS enumeration order: l1 outer, l2, l3) ----
__device__ const int P_L1[N_PATHS] = {0,0,0,0, 1,1,1,1,1,1, 2,2,2,2,2,2,2, 3,3,3,3,3,3};
__device__ const int P_L2[N_PATHS] = {0,1,2,3, 0,1,1,2,2,3, 0,1,1,2,2,3,3, 0,1,2,2,3,3};
__device__ const int P_L3[N_PATHS] = {0,1,2,3, 1,0,2,1,3,2, 2,1,3,0,2,1,3, 3,2,1,3,0,2};
__device__ const int C_OFF[N_PATHS] = {0,1,10,35,84,93,102,147,192,297,402,427,472,577,602,727,832,1077,1126,1231,1336,1581,1630};
__device__ const int CNT_L3[4] = {4,6,7,6};
__device__ const int OFF3[4] = {0,32,128,288};

// ---- 16-point Gauss-Legendre nodes/weights ----
__device__ const double GLX[16] = {
    -0.98940093499164993, -0.94457502307323258, -0.86563120238783174, -0.75540440835500303,
    -0.61787624440264375, -0.45801677765722739, -0.28160355077925891, -0.09501250983763744,
     0.09501250983763744,  0.28160355077925891,  0.45801677765722739,  0.61787624440264375,
     0.75540440835500303,  0.86563120238783174,  0.94457502307323258,  0.98940093499164993};
__device__ const double GLW[16] = {
     0.02715245941175409,  0.06225352393864789,  0.09515851168249278,  0.12462897125553387,
     0.14959598881657673,  0.16915651939500254,  0.18260341504492359,  0.18945061045506850,
     0.18945061045506850,  0.18260341504492359,  0.16915651939500254,  0.14959598881657673,
     0.12462897125553387,  0.09515851168249278,  0.06225352393864789,  0.02715245941175409};

// cos/sin(k*pi/16), k=0..31 — exact literals, no device transcendentals
__device__ const double COSP[32] = {
  1.0,                    0.980785280403230449,  0.923879532511286756,  0.831469612302545237,
  0.707106781186547524,   0.555570233019602225,  0.382683432365089772,  0.195090322016128268,
  0.0,                   -0.195090322016128268, -0.382683432365089772, -0.555570233019602225,
 -0.707106781186547524,  -0.831469612302545237, -0.923879532511286756, -0.980785280403230449,
 -1.0,                   -0.980785280403230449, -0.923879532511286756, -0.831469612302545237,
 -0.707106781186547524,  -0.555570233019602225, -0.382683432365089772, -0.195090322016128268,
  0.0,                    0.195090322016128268,  0.382683432365089772,  0.555570233019602225,
  0.707106781186547524,   0.831469612302545237,  0.923879532511286756,  0.980785280403230449};
__device__ const double SINP[32] = {
  0.0,                    0.195090322016128268,  0.382683432365089772,  0.555570233019602225,
  0.707106781186547524,   0.831469612302545237,  0.923879532511286756,  0.980785280403230449,
  1.0,                    0.980785280403230449,  0.923879532511286756,  0.831469612302545237,
  0.707106781186547524,   0.555570233019602225,  0.382683432365089772,  0.195090322016128268,
  0.0,                   -0.195090322016128268, -0.382683432365089772, -0.555570233019602225,
 -0.707106781186547524,  -0.831469612302545237, -0.923879532511286756, -0.980785280403230449,
 -1.0,                   -0.980785280403230449, -0.923879532511286756, -0.831469612302545237,
 -0.707106781186547524,  -0.555570233019602225, -0.382683432365089772, -0.195090322016128268};

__device__ inline void sh_f64(double x, double y, double z, double* Y) {
    const double s3 = 1.7320508075688772935, s5 = 2.2360679774997896964,
                 s7 = 2.6457513110645905905, s15 = 3.8729833462074168852;
    const double c58 = 0.79056941504209483300, c38 = 0.61237243569579452455;
    Y[0] = 1.0;
    Y[1] = s3*x;  Y[2] = s3*y;  Y[3] = s3*z;
    Y[4] = s5*s3*x*z;
    Y[5] = s5*s3*x*y;
    Y[6] = s5*(y*y - 0.5*(x*x + z*z));
    Y[7] = s5*s3*y*z;
    Y[8] = s5*(s3/2.0)*(z*z - x*x);
    Y[9] = s7*c58*x*(3.0*z*z - x*x);
    Y[10]= s7*s15*x*y*z;
    Y[11]= s7*c38*x*(5.0*y*y - 1.0);
    Y[12]= s7*0.5*y*(5.0*y*y - 3.0);
    Y[13]= s7*c38*z*(5.0*y*y - 1.0);
    Y[14]= s7*(s15/2.0)*y*(z*z - x*x);
    Y[15]= s7*c58*z*(z*z - 3.0*x*x);
}

__device__ inline void sh_f32(float x, float y, float z, float* Y) {
    const float s3 = 1.73205080757f, s5 = 2.23606797750f, s7 = 2.64575131106f, s15 = 3.87298334621f;
    const float c58 = 0.79056941504f, c38 = 0.61237243570f;
    Y[0] = 1.0f;
    Y[1] = s3*x;  Y[2] = s3*y;  Y[3] = s3*z;
    Y[4] = s15*x*z;
    Y[5] = s15*x*y;
    Y[6] = s5*(y*y - 0.5f*(x*x + z*z));
    Y[7] = s15*y*z;
    Y[8] = s5*(s3*0.5f)*(z*z - x*x);
    Y[9] = s7*c58*x*(3.0f*z*z - x*x);
    Y[10]= s7*s15*x*y*z;
    Y[11]= s7*c38*x*(5.0f*y*y - 1.0f);
    Y[12]= s7*0.5f*y*(5.0f*y*y - 3.0f);
    Y[13]= s7*c38*z*(5.0f*y*y - 1.0f);
    Y[14]= s7*(s15*0.5f)*y*(z*z - x*x);
    Y[15]= s7*c58*z*(z*z - 3.0f*x*x);
}

// ---- setup: build (PATH_W * W3J / ||W3J||) tables; quadrature Y staged in LDS ----
__global__ __launch_bounds__(256) void w3j_setup_kernel(float* __restrict__ g_w3j) {
    __shared__ float s_Yq[512][16];
    __shared__ float s_wq[512];
    __shared__ double red[256];
    __shared__ double s_scale;

    const int p = blockIdx.x;
    const int t = threadIdx.x;
    const int l1 = P_L1[p], l2 = P_L2[p], l3 = P_L3[p];
    const int d1 = 2*l1+1, d2 = 2*l2+1, d3 = 2*l3+1;
    const int csize = d1*d2*d3;

    const double step = 2.0*3.14159265358979323846/32.0;

#pragma unroll
    for (int r = 0; r < 2; ++r) {
        const int q = t + 256*r;
        const int iu = q >> 5, ip = q & 31;
        const double u = GLX[iu];
        const double st = sqrt(fmax(1.0 - u*u, 0.0));
        double Y[16];
        sh_f64(st*COSP[ip], st*SINP[ip], u, Y);
#pragma unroll
        for (int i = 0; i < 16; ++i) s_Yq[q][i] = (float)Y[i];
        s_wq[q] = (float)(GLW[iu] * step);
    }
    __syncthreads();

    const int idx0 = t, idx1 = t + 256;
    const bool v0 = idx0 < csize, v1 = idx1 < csize;
    int a0i=0,b0i=0,c0i=0, a1i=0,b1i=0,c1i=0;
    if (v0) { int i = idx0/(d2*d3); int r = idx0 - i*(d2*d3); int j = r/d3; int k = r - j*d3;
              a0i = l1*l1+i; b0i = l2*l2+j; c0i = l3*l3+k; }
    if (v1) { int i = idx1/(d2*d3); int r = idx1 - i*(d2*d3); int j = r/d3; int k = r - j*d3;
              a1i = l1*l1+i; b1i = l2*l2+j; c1i = l3*l3+k; }

    double a0 = 0.0, a1 = 0.0;
    for (int q = 0; q < 512; ++q) {
        const float wq = s_wq[q];
        if (v0) a0 += (double)(wq * s_Yq[q][a0i] * s_Yq[q][b0i] * s_Yq[q][c0i]);
        if (v1) a1 += (double)(wq * s_Yq[q][a1i] * s_Yq[q][b1i] * s_Yq[q][c1i]);
    }

    red[t] = a0*a0 + a1*a1;
    __syncthreads();
    for (int s = 128; s > 0; s >>= 1) {
        if (t < s) red[t] += red[t+s];
        __syncthreads();
    }
    if (t == 0) {
        const double nrm = sqrt(red[0]);
        const double pw  = sqrt((double)(2*l3+1) / ((double)CNT_L3[l3] * (double)HIDDEN));
        s_scale = pw / nrm;
    }
    __syncthreads();
    if (v0) g_w3j[C_OFF[p] + idx0] = (float)(a0 * s_scale);
    if (v1) g_w3j[C_OFF[p] + idx1] = (float)(a1 * s_scale);
}

// ---- per-path register-blocked GEMM: thread=(e,w), d3 outputs x2 in regs ----
template<int D3>
__device__ inline void gemm_path(int t, const float* __restrict__ s_tmp,
                                 const float* __restrict__ s_ww,
                                 const float* __restrict__ s_wb,
                                 const float* __restrict__ s_len,
                                 float* __restrict__ s_msg, int off3) {
    const int e = t >> 5, w = t & 31;
    const float* tp = s_tmp + e*256;   // [u][8]
    float accw[D3], accb[D3];
#pragma unroll
    for (int k = 0; k < D3; ++k) { accw[k] = 0.f; accb[k] = 0.f; }
#pragma unroll 4
    for (int u = 0; u < 32; ++u) {
        const float wwv = s_ww[u*32 + w];   // lanes w=0..31 -> banks 0..31, 2-way free
        const float wbv = s_wb[u*32 + w];
        const float* tu = tp + u*8;         // half-wave broadcast, b128-able
#pragma unroll
        for (int k = 0; k < D3; ++k) {
            const float tv = tu[k];
            accw[k] = fmaf(tv, wwv, accw[k]);
            accb[k] = fmaf(tv, wbv, accb[k]);
        }
    }
    const float len = s_len[e];
    float* mp = s_msg + e*FEAT + off3 + w*D3;   // unique owner -> no atomics
#pragma unroll
    for (int k = 0; k < D3; ++k) mp[k] += fmaf(len, accw[k], accb[k]);
}

// ---- main: 8 edges per block ----
__global__ __launch_bounds__(256) void edge_kernel(
    const float* __restrict__ nf,   // (N_NODES, FEAT)
    const int*   __restrict__ eidx, // (2, N_EDGES)
    const float* __restrict__ ev,   // (N_EDGES, 3)
    const float* __restrict__ ww,   // (23552,)
    const float* __restrict__ wb,   // (23552,)
    const float* __restrict__ w3j,  // (1875,)
    float*       __restrict__ out)  // (N_NODES, FEAT) pre-zeroed
{
    __shared__ float  s_x[EB*FEAT];      // 16 KB gathered features
    __shared__ float  s_msg[EB*FEAT];    // 16 KB message accumulator
    __shared__ float  s_tmp[EB*32*8];    // 8 KB per-path tmp, [e][u][8]
    __shared__ float4 s_ww4[256];        // 4 KB per-path ww
    __shared__ float4 s_wb4[256];        // 4 KB per-path wb
    __shared__ float  s_Cp[245];         // current path W3J
    __shared__ float  s_zp[EB*49];       // per-path z, [e][i*d3+k]
    __shared__ float  s_Y[EB*16];
    __shared__ float  s_len[EB];
    __shared__ int    s_src[EB];
    __shared__ int    s_dst[EB];

    const int t  = threadIdx.x;
    const int e0 = blockIdx.x * EB;

    // prologue: edge metadata + SH
    if (t < EB) {
        const int e = e0 + t;
        s_src[t] = eidx[e];
        s_dst[t] = eidx[N_EDGES + e];
        const float x = ev[e*3+0], y = ev[e*3+1], z = ev[e*3+2];
        const float len = sqrtf(x*x + y*y + z*z);
        const float lc = fmaxf(len, 1e-8f);
        s_len[t] = lc;
        float Yl[16];
        sh_f32(x/lc, y/lc, z/lc, Yl);
#pragma unroll
        for (int i = 0; i < 16; ++i) s_Y[t*16+i] = Yl[i];
    }
    for (int i = t; i < EB*FEAT; i += 256) s_msg[i] = 0.f;
    __syncthreads();

    // gather node features, float4-coalesced
    for (int i = t; i < EB*(FEAT/4); i += 256) {
        const int e = i >> 7, c = i & 127;
        ((float4*)s_x)[i] = ((const float4*)(nf + (size_t)s_src[e]*FEAT))[c];
    }

    const float* s_ww = (const float*)s_ww4;
    const float* s_wb = (const float*)s_wb4;

    for (int p = 0; p < N_PATHS; ++p) {
        const int l1 = P_L1[p], l2 = P_L2[p], l3 = P_L3[p];
        const int d1 = 2*l1+1, d2 = 2*l2+1, d3 = 2*l3+1;
        const int d23 = d2*d3, zc = d1*d3, csize = d1*d23;

        __syncthreads();  // protects s_ww/s_wb/s_Cp/s_tmp overwrite vs prev-path reads
        // stage weights (8 KB) + this path's C
        s_ww4[t] = ((const float4*)(ww + p*1024))[t];
        s_wb4[t] = ((const float4*)(wb + p*1024))[t];
        for (int i = t; i < csize; i += 256) s_Cp[i] = w3j[C_OFF[p] + i];
        __syncthreads();

        // z[e][i][k] = sum_j Y[e][l2^2+j] * C[i][j][k]
        for (int idx = t; idx < EB*zc; idx += 256) {
            const int e = idx / zc, r = idx - e*zc;
            const int i = r / d3, k = r - i*d3;
            const float* Cp = s_Cp + i*d23 + k;
            const float* Yp = s_Y + e*16 + l2*l2;
            float acc = 0.f;
            for (int j = 0; j < d2; ++j) acc = fmaf(Yp[j], Cp[j*d3], acc);
            s_zp[e*49 + r] = acc;
        }
        __syncthreads();

        // tmp[e][u][k] = sum_i x[e][32*l1^2 + u*d1 + i] * z[e][i][k]
        {
            const int e = t >> 5, u = t & 31;
            const float* xr = s_x + e*FEAT + HIDDEN*l1*l1 + u*d1;
            const float* zr = s_zp + e*49;
            float* tr = s_tmp + (e*32 + u)*8;
            for (int k = 0; k < d3; ++k) {
                float acc = 0.f;
                for (int i = 0; i < d1; ++i) acc = fmaf(xr[i], zr[i*d3 + k], acc);
                tr[k] = acc;
            }
        }
        __syncthreads();

        // GEMM: msg[e][off3 + w*d3 + k] += sum_u tmp[e][u][k]*(len*ww+wb)[u][w]
        switch (l3) {
            case 0: gemm_path<1>(t, s_tmp, s_ww, s_wb, s_len, s_msg, 0);   break;
            case 1: gemm_path<3>(t, s_tmp, s_ww, s_wb, s_len, s_msg, 32);  break;
            case 2: gemm_path<5>(t, s_tmp, s_ww, s_wb, s_len, s_msg, 128); break;
            default: gemm_path<7>(t, s_tmp, s_ww, s_wb, s_len, s_msg, 288); break;
        }
    }
    __syncthreads();

    // scatter: coalesced global atomics
    for (int i = t; i < EB*FEAT; i += 256) {
        const int e = i >> 9, m = i & 511;
        atomicAdd(&out[(size_t)s_dst[e]*FEAT + m], s_msg[i]);
    }
}

extern "C" void kernel_launch(void* const* d_in, const int* in_sizes, int n_in,
                              void* d_out, int out_size, void* d_ws, size_t ws_size,
                              hipStream_t stream) {
    const float* nf   = (const float*)d_in[0];
    const int*   eidx = (const int*)  d_in[1];
    const float* ev   = (const float*)d_in[2];
    const float* ww   = (const float*)d_in[3];
    const float* wb   = (const float*)d_in[4];
    float* out  = (float*)d_out;
    float* w3j  = (float*)d_ws;

    hipMemsetAsync(d_out, 0, (size_t)out_size * sizeof(float), stream);
    w3j_setup_kernel<<<N_PATHS, 256, 0, stream>>>(w3j);
    edge_kernel<<<N_EDGES/EB, 256, 0, stream>>>(nf, eidx, ev, ww, wb, w3j, out);
}